// Round 4
// baseline (5581.728 us; speedup 1.0000x reference)
//
#include <hip/hip_runtime.h>
#include <hip/hip_bf16.h>

// Sizes (fixed by the problem)
#define B    64
#define P    196      // 14*14
#define DENC 2048
#define AA   512
#define EE   512
#define HH   512
#define VV   10000
#define LL   24
#define TT   23       // L-1

typedef unsigned short u16;
typedef unsigned int   u32;
typedef __bf16 bf16x8 __attribute__((ext_vector_type(8)));
typedef float  f32x4  __attribute__((ext_vector_type(4)));

__device__ __forceinline__ float wave_sum(float v) {
    #pragma unroll
    for (int o = 32; o > 0; o >>= 1) v += __shfl_xor(v, o, 64);
    return v;
}
__device__ __forceinline__ float sigmoidf(float x) {
    return 1.0f / (1.0f + __expf(-x));
}
// RNE fp32 -> bf16
__device__ __forceinline__ u16 f2b(float x) {
    u32 v = __float_as_uint(x); v += 0x7FFFu + ((v >> 16) & 1u); return (u16)(v >> 16);
}
__device__ __forceinline__ float b2f(u16 x) {
    return __uint_as_float(((u32)x) << 16);
}
__device__ __forceinline__ u32 pk2(float x, float y) {
    return (u32)f2b(x) | ((u32)f2b(y) << 16);
}
__device__ __forceinline__ float dot8f(const float* __restrict__ w, const float hreg[8]) {
    float4 w0 = *(const float4*)w, w1 = *(const float4*)(w + 4);
    return hreg[0]*w0.x + hreg[1]*w0.y + hreg[2]*w0.z + hreg[3]*w0.w
         + hreg[4]*w1.x + hreg[5]*w1.y + hreg[6]*w1.z + hreg[7]*w1.w;
}

// ---------------- mean over P ----------------
__global__ __launch_bounds__(256) void mean_kernel(const float* __restrict__ enc, float* __restrict__ mean) {
    int b = blockIdx.y;
    int d = blockIdx.x * 256 + threadIdx.x;
    const float* e = enc + (long)b * P * DENC + d;
    float s = 0.f;
    #pragma unroll 4
    for (int p = 0; p < P; ++p) s += e[(long)p * DENC];
    mean[b * DENC + d] = s * (1.0f / (float)P);
}

// ---------------- h0/c0 init: wave per output ----------------
__global__ __launch_bounds__(256) void h0c0_kernel(const float* __restrict__ mean,
                                                   const float* __restrict__ W_h0, const float* __restrict__ b_h0,
                                                   const float* __restrict__ W_c0, const float* __restrict__ b_c0,
                                                   float* __restrict__ h, float* __restrict__ c,
                                                   u16* __restrict__ h_bf) {
    int w = blockIdx.x * 4 + (threadIdx.x >> 6);   // 0..65535
    int lane = threadIdx.x & 63;
    int sel = w >> 15;            // 0: h0, 1: c0
    int r = w & 32767;
    int j = r >> 6, b = r & 63;
    const float4* mp = (const float4*)(mean + b * DENC);
    const float4* wp = (const float4*)((sel ? W_c0 : W_h0) + (long)j * DENC);
    float s = 0.f;
    for (int i = lane; i < DENC / 4; i += 64) {
        float4 x = mp[i], y = wp[i];
        s += x.x * y.x + x.y * y.y + x.z * y.z + x.w * y.w;
    }
    s = wave_sum(s);
    if (lane == 0) {
        float v = s + (sel ? b_c0[j] : b_h0[j]);
        if (sel) c[b * HH + j] = v;
        else { h[b * HH + j] = v; h_bf[b * HH + j] = f2b(v); }
    }
}

// ---------------- prologue: bf16 conversions + weight rearrange + emb gather ----------------
__global__ __launch_bounds__(256) void prep_kernel(
    const float* __restrict__ enc, const float* __restrict__ W_ih, const float* __restrict__ W_hh,
    const float* __restrict__ b_ih, const float* __restrict__ b_hh,
    const float* __restrict__ emb, const int* __restrict__ cap,
    u16* __restrict__ enc_bf, u16* __restrict__ Wg_bf, u16* __restrict__ xemb, float* __restrict__ gbias)
{
    const long NU_ENC = 3211264;   // 64*196*2048/8
    const long NU_WG  = 786432;    // 2048*3072/8
    const long NU_XE  = 94208;     // 23*64*512/8
    const long NU_GB  = 256;       // 2048/8
    const long NTOT = NU_ENC + NU_WG + NU_XE + NU_GB;
    long stride = (long)gridDim.x * 256;
    for (long u = (long)blockIdx.x * 256 + threadIdx.x; u < NTOT; u += stride) {
        if (u < NU_ENC) {
            const float* s = enc + u * 8;
            float4 a = *(const float4*)s, bb = *(const float4*)(s + 4);
            ((uint4*)enc_bf)[u] = make_uint4(pk2(a.x, a.y), pk2(a.z, a.w), pk2(bb.x, bb.y), pk2(bb.z, bb.w));
        } else if (u < NU_ENC + NU_WG) {
            long q = u - NU_ENC;
            long rw = q / 384;               // tile-row 0..2047 = wg*64 + r
            int k8 = (int)(q % 384) * 8;
            int wgt = (int)(rw >> 6), r = (int)(rw & 63);
            int gr = ((r >> 4) << 9) + (wgt << 4) + (r & 15);  // type*512 + wg*16 + jj
            const float* s = (k8 < 2560) ? (W_ih + (long)gr * 2560 + k8)
                                         : (W_hh + (long)gr * 512 + (k8 - 2560));
            float4 a = *(const float4*)s, bb = *(const float4*)(s + 4);
            ((uint4*)Wg_bf)[q] = make_uint4(pk2(a.x, a.y), pk2(a.z, a.w), pk2(bb.x, bb.y), pk2(bb.z, bb.w));
        } else if (u < NU_ENC + NU_WG + NU_XE) {
            long q = u - NU_ENC - NU_WG;
            int ku = (int)(q & 63);          // 8-elem chunk within 512
            int b  = (int)((q >> 6) & 63);
            int t  = (int)(q >> 12);         // /4096
            int tok = cap[b * LL + t];
            const float* s = emb + (long)tok * EE + ku * 8;
            float4 a = *(const float4*)s, bb = *(const float4*)(s + 4);
            ((uint4*)xemb)[q] = make_uint4(pk2(a.x, a.y), pk2(a.z, a.w), pk2(bb.x, bb.y), pk2(bb.z, bb.w));
        } else {
            long q = u - NU_ENC - NU_WG - NU_XE;
            int i0 = (int)q * 8;
            #pragma unroll
            for (int j = 0; j < 8; ++j) gbias[i0 + j] = b_ih[i0 + j] + b_hh[i0 + j];
        }
    }
}

// ---------------- bf16 MFMA GEMM: C = A(MxK) * B(NxK)^T + bias ----------------
// ABF16: A is bf16 in memory. CBF16: write bf16 output (Cbf) instead of fp32 C.
template<bool ABF16, bool CBF16>
__global__ __launch_bounds__(256) void gemm_bf16_kernel(
    const void* __restrict__ Av, int lda,
    const float* __restrict__ Bm, int ldb,
    const float* __restrict__ bias,
    float* __restrict__ C, u16* __restrict__ Cbf, int ldc,
    int M, int N, int K,
    const int* __restrict__ caplen, int Tsteps)
{
    __shared__ __align__(16) u16 As[128 * 32];
    __shared__ __align__(16) u16 Bs[128 * 32];
    const int tid  = threadIdx.x;
    const int lane = tid & 63;
    const int w    = tid >> 6;
    const int wr   = w >> 1, wc = w & 1;
    const int bm = blockIdx.y * 128;
    const int bn = blockIdx.x * 128;

    f32x4 acc[4][4];
    #pragma unroll
    for (int m = 0; m < 4; ++m)
        #pragma unroll
        for (int n = 0; n < 4; ++n) acc[m][n] = (f32x4)0.f;

    const int srow = tid >> 1;
    const int scol = (tid & 1) * 16;
    long arow = bm + srow; if (arow >= M) arow = M - 1;
    long brow = bn + srow; if (brow >= N) brow = N - 1;
    const float* apf = ABF16 ? nullptr : (const float*)Av + arow * (long)lda + scol;
    const u16*   apb = ABF16 ? (const u16*)Av + arow * (long)lda + scol : nullptr;
    const float* bp  = Bm + brow * (long)ldb + scol;

    float4 ra[4], rb[4];
    uint4  rab[2];
    if (ABF16) { rab[0] = *(const uint4*)apb; rab[1] = *(const uint4*)(apb + 8); }
    else {
        #pragma unroll
        for (int i = 0; i < 4; ++i) ra[i] = *(const float4*)(apf + 4 * i);
    }
    #pragma unroll
    for (int i = 0; i < 4; ++i) rb[i] = *(const float4*)(bp + 4 * i);

    const int nk = K / 32;
    const int fr = lane & 15;
    const int kc = (lane >> 4) * 8;

    for (int kt = 0; kt < nk; ++kt) {
        uint4 pa0, pa1;
        if (ABF16) { pa0 = rab[0]; pa1 = rab[1]; }
        else {
            pa0 = make_uint4(pk2(ra[0].x, ra[0].y), pk2(ra[0].z, ra[0].w), pk2(ra[1].x, ra[1].y), pk2(ra[1].z, ra[1].w));
            pa1 = make_uint4(pk2(ra[2].x, ra[2].y), pk2(ra[2].z, ra[2].w), pk2(ra[3].x, ra[3].y), pk2(ra[3].z, ra[3].w));
        }
        uint4 pb0 = make_uint4(pk2(rb[0].x, rb[0].y), pk2(rb[0].z, rb[0].w), pk2(rb[1].x, rb[1].y), pk2(rb[1].z, rb[1].w));
        uint4 pb1 = make_uint4(pk2(rb[2].x, rb[2].y), pk2(rb[2].z, rb[2].w), pk2(rb[3].x, rb[3].y), pk2(rb[3].z, rb[3].w));
        __syncthreads();
        *(uint4*)&As[srow * 32 + scol]     = pa0;
        *(uint4*)&As[srow * 32 + scol + 8] = pa1;
        *(uint4*)&Bs[srow * 32 + scol]     = pb0;
        *(uint4*)&Bs[srow * 32 + scol + 8] = pb1;
        if (kt + 1 < nk) {
            bp += 32;
            if (ABF16) { apb += 32; rab[0] = *(const uint4*)apb; rab[1] = *(const uint4*)(apb + 8); }
            else {
                apf += 32;
                #pragma unroll
                for (int i = 0; i < 4; ++i) ra[i] = *(const float4*)(apf + 4 * i);
            }
            #pragma unroll
            for (int i = 0; i < 4; ++i) rb[i] = *(const float4*)(bp + 4 * i);
        }
        __syncthreads();
        bf16x8 a[4], bfr[4];
        #pragma unroll
        for (int m = 0; m < 4; ++m)
            a[m] = *(const bf16x8*)&As[(wr * 64 + m * 16 + fr) * 32 + kc];
        #pragma unroll
        for (int n = 0; n < 4; ++n)
            bfr[n] = *(const bf16x8*)&Bs[(wc * 64 + n * 16 + fr) * 32 + kc];
        #pragma unroll
        for (int m = 0; m < 4; ++m)
            #pragma unroll
            for (int n = 0; n < 4; ++n)
                acc[m][n] = __builtin_amdgcn_mfma_f32_16x16x32_bf16(a[m], bfr[n], acc[m][n], 0, 0, 0);
    }

    const int cr = lane >> 4;
    const int cc = lane & 15;
    #pragma unroll
    for (int n = 0; n < 4; ++n) {
        int gn = bn + wc * 64 + n * 16 + cc;
        if (gn >= N) continue;
        float bv = bias[gn];
        #pragma unroll
        for (int m = 0; m < 4; ++m) {
            int gm0 = bm + wr * 64 + m * 16 + cr * 4;
            #pragma unroll
            for (int r = 0; r < 4; ++r) {
                int gm = gm0 + r;
                if (gm >= M) continue;
                float rowscale = 1.f;
                if (caplen) {
                    int b = gm / Tsteps, tt = gm - b * Tsteps;
                    if (tt >= caplen[b] - 1) rowscale = 0.f;
                }
                float v = (acc[m][n][r] + bv) * rowscale;
                if (CBF16) Cbf[(long)gm * ldc + gn] = f2b(v);
                else       C[(long)gm * ldc + gn] = v;
            }
        }
    }
}

// ---------------- Phase B: hid[b] (in-LDS) + att[b,p] ----------------
// grid 256 wgs: wg w -> b = w>>2, p-range (w&3)*49..+49
__global__ __launch_bounds__(256) void phaseB_kernel(
    const float* __restrict__ h, const float* __restrict__ W_hid, const float* __restrict__ b_hid,
    const u16* __restrict__ enc_att_bf, const float* __restrict__ wf, const float* __restrict__ bfull,
    float* __restrict__ att)
{
    __shared__ float hidS[AA];
    const int tid = threadIdx.x, lane = tid & 63, v = tid >> 6;
    const int b = blockIdx.x >> 2, pq = blockIdx.x & 3;

    float hreg[8];
    {
        const float4* hp = (const float4*)(h + b * HH + lane * 8);
        float4 h0 = hp[0], h1 = hp[1];
        hreg[0]=h0.x; hreg[1]=h0.y; hreg[2]=h0.z; hreg[3]=h0.w;
        hreg[4]=h1.x; hreg[5]=h1.y; hreg[6]=h1.z; hreg[7]=h1.w;
    }
    // hid: wave v computes a = v*128 .. +128 (redundant across the 4 wgs of b)
    #pragma unroll 2
    for (int i = 0; i < 128; ++i) {
        int a = v * 128 + i;
        float s = dot8f(W_hid + (long)a * HH + lane * 8, hreg);
        s = wave_sum(s);
        if (lane == 0) hidS[a] = s + b_hid[a];
    }
    __syncthreads();
    float hid8[8], wfr[8];
    #pragma unroll
    for (int i = 0; i < 8; ++i) { hid8[i] = hidS[lane * 8 + i]; wfr[i] = wf[lane * 8 + i]; }

    for (int i = v; i < 49; i += 4) {
        int p = pq * 49 + i;
        const uint4 e = *(const uint4*)(enc_att_bf + ((long)(b * P + p)) * AA + lane * 8);
        u32 wd[4] = {e.x, e.y, e.z, e.w};
        float s = 0.f;
        #pragma unroll
        for (int q = 0; q < 4; ++q) {
            float lo = b2f((u16)wd[q]) + hid8[2 * q];
            float hi = b2f((u16)(wd[q] >> 16)) + hid8[2 * q + 1];
            lo = lo > 0.f ? lo : 0.f;
            hi = hi > 0.f ? hi : 0.f;
            s += lo * wfr[2 * q] + hi * wfr[2 * q + 1];
        }
        s = wave_sum(s);
        if (lane == 0) att[b * P + p] = s + bfull[0];
    }
}

// ---------------- Phase C: softmax + out_att + gatevec + ctx ----------------
// grid 256 wgs: wg w -> b = w>>2, d-slice (w&3)*512..+512
__global__ __launch_bounds__(256) void phaseC_kernel(
    const float* __restrict__ att, const float* __restrict__ h,
    const float* __restrict__ W_beta, const float* __restrict__ b_beta,
    const u16* __restrict__ enc_bf, u16* __restrict__ ctx_bf,
    float* __restrict__ out_att, const int* __restrict__ caplen, int t)
{
    __shared__ float awS[P];
    __shared__ float gvS[512];
    __shared__ float red[4];
    const int tid = threadIdx.x, lane = tid & 63, v = tid >> 6;
    const int b = blockIdx.x >> 2, q = blockIdx.x & 3;
    const int d0 = q * 512;

    // softmax (redundant per wg; cheap: 196 elems)
    float val = (tid < P) ? att[b * P + tid] : -1e30f;
    float m = val;
    #pragma unroll
    for (int o = 32; o > 0; o >>= 1) m = fmaxf(m, __shfl_xor(m, o, 64));
    if (lane == 0) red[v] = m;
    __syncthreads();
    m = fmaxf(fmaxf(red[0], red[1]), fmaxf(red[2], red[3]));
    float e = (tid < P) ? __expf(val - m) : 0.f;
    float ssum = wave_sum(e);
    __syncthreads();
    if (lane == 0) red[v] = ssum;
    __syncthreads();
    float stot = red[0] + red[1] + red[2] + red[3];
    if (tid < P) {
        float a = e / stot;
        awS[tid] = a;
        if (q == 0) out_att[((long)b * TT + t) * P + tid] = (t < caplen[b] - 1) ? a : 0.f;
    }

    // gatevec = sigmoid(h @ W_beta^T + b_beta) for d-slice
    float hreg[8];
    {
        const float4* hp = (const float4*)(h + b * HH + lane * 8);
        float4 h0 = hp[0], h1 = hp[1];
        hreg[0]=h0.x; hreg[1]=h0.y; hreg[2]=h0.z; hreg[3]=h0.w;
        hreg[4]=h1.x; hreg[5]=h1.y; hreg[6]=h1.z; hreg[7]=h1.w;
    }
    #pragma unroll 2
    for (int i = 0; i < 128; ++i) {
        int dl = v * 128 + i;
        float s = dot8f(W_beta + (long)(d0 + dl) * HH + lane * 8, hreg);
        s = wave_sum(s);
        if (lane == 0) gvS[dl] = sigmoidf(s + b_beta[d0 + dl]);
    }
    __syncthreads();

    // ctx: thread handles 2 adjacent d's
    const u16* ebase = enc_bf + (long)b * (P * DENC) + d0 + tid * 2;
    float s0 = 0.f, s1 = 0.f;
    #pragma unroll 4
    for (int p = 0; p < P; ++p) {
        u32 uu = *(const u32*)(ebase + (long)p * DENC);
        float a = awS[p];
        s0 += b2f((u16)uu) * a;
        s1 += b2f((u16)(uu >> 16)) * a;
    }
    float g0 = gvS[tid * 2], g1 = gvS[tid * 2 + 1];
    *(u32*)(ctx_bf + (long)b * DENC + d0 + tid * 2) = pk2(s0 * g0, s1 * g1);
}

// ---------------- Phase D: gates GEMM (MFMA) + LSTM pointwise, fused ----------------
// grid 32 wgs: wg owns gate-rows {type*512 + wg*16 + jj : type<4, jj<16} for all 64 b.
__global__ __launch_bounds__(256) void phaseD_kernel(
    const u16* __restrict__ xemb_t, const u16* __restrict__ ctx_bf, u16* __restrict__ h_bf,
    const u16* __restrict__ Wg_bf, const float* __restrict__ gbias,
    float* __restrict__ h, float* __restrict__ c, u16* __restrict__ Hst_bf,
    const int* __restrict__ caplen, int t)
{
    __shared__ __align__(16) u16 As[64 * 128];   // 16KB, swizzled
    __shared__ __align__(16) u16 Bs[64 * 128];   // 16KB
    __shared__ float Gs[64 * 65];                // 16.6KB
    const int tid = threadIdx.x, lane = tid & 63, v = tid >> 6;
    const int wg = blockIdx.x;

    f32x4 acc[4];
    #pragma unroll
    for (int m = 0; m < 4; ++m) acc[m] = (f32x4)0.f;

    const int srow = tid >> 2;            // 0..63
    const int se = (tid & 3) * 32;        // k-elem offset within BK=128
    const u16* wsrc = Wg_bf + ((long)wg * 64 + srow) * 3072 + se;

    auto asrcAt = [&](int k0) -> const u16* {
        int k = k0 + se;
        if (k < 512)  return xemb_t + srow * EE + k;
        if (k < 2560) return ctx_bf + srow * DENC + (k - 512);
        return h_bf + srow * HH + (k - 2560);
    };

    uint4 ra[4], rw[4];
    {
        const u16* as = asrcAt(0);
        #pragma unroll
        for (int i = 0; i < 4; ++i) { ra[i] = *(const uint4*)(as + 8 * i); rw[i] = *(const uint4*)(wsrc + 8 * i); }
    }

    const int swz = (srow & 7) << 4;
    for (int kt = 0; kt < 24; ++kt) {
        __syncthreads();
        #pragma unroll
        for (int i = 0; i < 4; ++i) {
            int cb = se * 2 + i * 16;
            *(uint4*)((char*)As + srow * 256 + (cb ^ swz)) = ra[i];
            *(uint4*)((char*)Bs + srow * 256 + (cb ^ swz)) = rw[i];
        }
        if (kt + 1 < 24) {
            int k0n = (kt + 1) * 128;
            const u16* as = asrcAt(k0n);
            const u16* ws = wsrc + k0n;
            #pragma unroll
            for (int i = 0; i < 4; ++i) { ra[i] = *(const uint4*)(as + 8 * i); rw[i] = *(const uint4*)(ws + 8 * i); }
        }
        __syncthreads();
        #pragma unroll
        for (int kf = 0; kf < 4; ++kf) {
            int fb = kf * 64 + (lane >> 4) * 16;
            int rb_ = v * 16 + (lane & 15);
            bf16x8 bfrag = *(const bf16x8*)((char*)Bs + rb_ * 256 + (fb ^ ((rb_ & 7) << 4)));
            #pragma unroll
            for (int m = 0; m < 4; ++m) {
                int rowa = m * 16 + (lane & 15);
                bf16x8 afrag = *(const bf16x8*)((char*)As + rowa * 256 + (fb ^ ((rowa & 7) << 4)));
                acc[m] = __builtin_amdgcn_mfma_f32_16x16x32_bf16(afrag, bfrag, acc[m], 0, 0, 0);
            }
        }
    }

    // acc -> Gs[r][b] (r = tile gate-row, b = batch)
    {
        int r = v * 16 + (lane & 15);
        #pragma unroll
        for (int m = 0; m < 4; ++m) {
            int brow = m * 16 + (lane >> 4) * 4;
            #pragma unroll
            for (int rg = 0; rg < 4; ++rg)
                Gs[r * 65 + brow + rg] = acc[m][rg];
        }
    }
    __syncthreads();

    // LSTM pointwise for this wg's 16 j's, all 64 b
    const int b = lane;
    #pragma unroll
    for (int i = 0; i < 4; ++i) {
        int jj = v * 4 + i;
        int j = wg * 16 + jj;
        float gi = Gs[jj * 65 + b]        + gbias[j];
        float gf = Gs[(16 + jj) * 65 + b] + gbias[512 + j];
        float gg = Gs[(32 + jj) * 65 + b] + gbias[1024 + j];
        float go = Gs[(48 + jj) * 65 + b] + gbias[1536 + j];
        float cold = c[b * HH + j];
        float cn = sigmoidf(gf) * cold + sigmoidf(gi) * tanhf(gg);
        float hn = sigmoidf(go) * tanhf(cn);
        Hst_bf[((long)b * TT + t) * HH + j] = f2b(hn);
        if (t < caplen[b] - 1) {
            h[b * HH + j] = hn;
            c[b * HH + j] = cn;
            h_bf[b * HH + j] = f2b(hn);
        }
    }
}

// ---------------- meta outputs ----------------
__global__ __launch_bounds__(256) void meta_kernel(const int* __restrict__ cap, const int* __restrict__ caplen,
                                                   float* __restrict__ out_cap, float* __restrict__ out_len) {
    int i = blockIdx.x * 256 + threadIdx.x;
    if (i < B * LL) out_cap[i] = (float)cap[i];
    if (i < B) out_len[i] = (float)(caplen[i] - 1);
}

extern "C" void kernel_launch(void* const* d_in, const int* in_sizes, int n_in,
                              void* d_out, int out_size, void* d_ws, size_t ws_size,
                              hipStream_t stream) {
    const float* enc    = (const float*)d_in[0];
    const int*   cap    = (const int*)d_in[1];
    const int*   caplen = (const int*)d_in[2];
    const float* emb    = (const float*)d_in[3];
    const float* W_enc  = (const float*)d_in[4];
    const float* b_enc  = (const float*)d_in[5];
    const float* W_hid  = (const float*)d_in[6];
    const float* b_hid  = (const float*)d_in[7];
    const float* w_full = (const float*)d_in[8];
    const float* b_full = (const float*)d_in[9];
    const float* W_ih   = (const float*)d_in[10];
    const float* b_ih   = (const float*)d_in[11];
    const float* W_hh   = (const float*)d_in[12];
    const float* b_hh   = (const float*)d_in[13];
    const float* W_h0   = (const float*)d_in[14];
    const float* b_h0   = (const float*)d_in[15];
    const float* W_c0   = (const float*)d_in[16];
    const float* b_c0   = (const float*)d_in[17];
    const float* W_beta = (const float*)d_in[18];
    const float* b_beta = (const float*)d_in[19];
    const float* W_fc   = (const float*)d_in[20];
    const float* b_fc   = (const float*)d_in[21];

    float* out = (float*)d_out;
    float* out_pred = out;                                  // 14,720,000
    float* out_cap  = out + 14720000;                       // 1536
    float* out_len  = out + 14721536;                       // 64
    float* out_att  = out + 14721600;                       // 288,512

    // enc_bf lives in the (not-yet-written) out_pred region: 25,690,112 bf16 = 51.4MB <= 58.9MB
    u16* enc_bf = (u16*)out_pred;

    float* ws = (float*)d_ws;
    u16*   Wg_bf      = (u16*)ws;                    // 6,291,456 u16 = 3,145,728 fl
    u16*   xemb       = (u16*)(ws + 3145728);        // 753,664 u16 = 376,832 fl
    float* gbias      = ws + 3522560;                // 2048
    float* mean       = ws + 3524608;                // 131,072
    float* h          = ws + 3655680;                // 32,768
    float* c          = ws + 3688448;                // 32,768
    u16*   h_bf       = (u16*)(ws + 3721216);        // 16,384 fl
    u16*   ctx_bf     = (u16*)(ws + 3737600);        // 65,536 fl
    float* att        = ws + 3803136;                // 12,544
    u16*   Hst_bf     = (u16*)(ws + 3815680);        // 376,832 fl
    u16*   enc_att_bf = (u16*)(ws + 4192512);        // 3,211,264 fl -> total 7,403,776 fl = 29.6MB

    // ---- prologue ----
    mean_kernel<<<dim3(DENC / 256, B), 256, 0, stream>>>(enc, mean);
    h0c0_kernel<<<16384, 256, 0, stream>>>(mean, W_h0, b_h0, W_c0, b_c0, h, c, h_bf);
    prep_kernel<<<4096, 256, 0, stream>>>(enc, W_ih, W_hh, b_ih, b_hh, emb, cap,
                                          enc_bf, Wg_bf, xemb, gbias);
    gemm_bf16_kernel<false, true><<<dim3(AA / 128, (B * P) / 128), 256, 0, stream>>>(
        enc, DENC, W_enc, DENC, b_enc, nullptr, enc_att_bf, AA, B * P, AA, DENC, nullptr, 0);
    meta_kernel<<<(B * LL + 255) / 256, 256, 0, stream>>>(cap, caplen, out_cap, out_len);

    // ---- recurrent steps: 3 launches per step ----
    for (int t = 0; t < TT; ++t) {
        phaseB_kernel<<<256, 256, 0, stream>>>(h, W_hid, b_hid, enc_att_bf, w_full, b_full, att);
        phaseC_kernel<<<256, 256, 0, stream>>>(att, h, W_beta, b_beta, enc_bf, ctx_bf, out_att, caplen, t);
        phaseD_kernel<<<32, 256, 0, stream>>>(xemb + (long)t * B * EE, ctx_bf, h_bf,
                                              Wg_bf, gbias, h, c, Hst_bf, caplen, t);
    }

    // ---- deferred vocab FC: preds = Hst(1472x512,bf16) @ W_fc(10000x512)^T + b_fc ----
    gemm_bf16_kernel<true, false><<<dim3((VV + 127) / 128, (B * TT + 127) / 128), 256, 0, stream>>>(
        Hst_bf, HH, W_fc, HH, b_fc, out_pred, nullptr, VV, B * TT, VV, HH, caplen, TT);
}

// Round 5
// 2507.008 us; speedup vs baseline: 2.2265x; 2.2265x over previous
//
#include <hip/hip_runtime.h>
#include <hip/hip_bf16.h>

// Sizes (fixed by the problem)
#define B    64
#define P    196      // 14*14
#define DENC 2048
#define AA   512
#define EE   512
#define HH   512
#define VV   10000
#define LL   24
#define TT   23       // L-1

typedef unsigned short u16;
typedef unsigned int   u32;
typedef __bf16 bf16x8 __attribute__((ext_vector_type(8)));
typedef float  f32x4  __attribute__((ext_vector_type(4)));

__device__ __forceinline__ float wave_sum(float v) {
    #pragma unroll
    for (int o = 32; o > 0; o >>= 1) v += __shfl_xor(v, o, 64);
    return v;
}
__device__ __forceinline__ float sigmoidf(float x) {
    return 1.0f / (1.0f + __expf(-x));
}
// RNE fp32 -> bf16
__device__ __forceinline__ u16 f2b(float x) {
    u32 v = __float_as_uint(x); v += 0x7FFFu + ((v >> 16) & 1u); return (u16)(v >> 16);
}
__device__ __forceinline__ float b2f(u16 x) {
    return __uint_as_float(((u32)x) << 16);
}
__device__ __forceinline__ u32 pk2(float x, float y) {
    return (u32)f2b(x) | ((u32)f2b(y) << 16);
}

// ---------------- mean over P ----------------
__global__ __launch_bounds__(256) void mean_kernel(const float* __restrict__ enc, float* __restrict__ mean) {
    int b = blockIdx.y;
    int d = blockIdx.x * 256 + threadIdx.x;
    const float* e = enc + (long)b * P * DENC + d;
    float s = 0.f;
    #pragma unroll 4
    for (int p = 0; p < P; ++p) s += e[(long)p * DENC];
    mean[b * DENC + d] = s * (1.0f / (float)P);
}

// ---------------- h0/c0 init: wave per output ----------------
__global__ __launch_bounds__(256) void h0c0_kernel(const float* __restrict__ mean,
                                                   const float* __restrict__ W_h0, const float* __restrict__ b_h0,
                                                   const float* __restrict__ W_c0, const float* __restrict__ b_c0,
                                                   float* __restrict__ c, u16* __restrict__ h_bf) {
    int w = blockIdx.x * 4 + (threadIdx.x >> 6);   // 0..65535
    int lane = threadIdx.x & 63;
    int sel = w >> 15;            // 0: h0, 1: c0
    int r = w & 32767;
    int j = r >> 6, b = r & 63;
    const float4* mp = (const float4*)(mean + b * DENC);
    const float4* wp = (const float4*)((sel ? W_c0 : W_h0) + (long)j * DENC);
    float s = 0.f;
    for (int i = lane; i < DENC / 4; i += 64) {
        float4 x = mp[i], y = wp[i];
        s += x.x * y.x + x.y * y.y + x.z * y.z + x.w * y.w;
    }
    s = wave_sum(s);
    if (lane == 0) {
        float v = s + (sel ? b_c0[j] : b_h0[j]);
        if (sel) c[b * HH + j] = v;
        else     h_bf[b * HH + j] = f2b(v);
    }
}

// ---------------- prologue: bf16 conversions + weight rearrange + emb gather ----------------
__global__ __launch_bounds__(256) void prep_kernel(
    const float* __restrict__ enc, const float* __restrict__ W_ih, const float* __restrict__ W_hh,
    const float* __restrict__ b_ih, const float* __restrict__ b_hh,
    const float* __restrict__ emb, const int* __restrict__ cap,
    const float* __restrict__ W_hid, const float* __restrict__ W_beta,
    const float* __restrict__ b_hid, const float* __restrict__ b_beta,
    u16* __restrict__ enc_bf, u16* __restrict__ Wg_bf, u16* __restrict__ xemb, float* __restrict__ gbias,
    u16* __restrict__ Whg_bf, float* __restrict__ bhg)
{
    const long NU_ENC = 3211264;   // 64*196*2048/8
    const long NU_WG  = 786432;    // 2048*3072/8
    const long NU_XE  = 94208;     // 23*64*512/8
    const long NU_GB  = 256;       // 2048/8
    const long NU_WHG = 163840;    // 2560*512/8
    const long NU_BHG = 320;       // 2560/8
    const long NTOT = NU_ENC + NU_WG + NU_XE + NU_GB + NU_WHG + NU_BHG;
    long stride = (long)gridDim.x * 256;
    for (long u = (long)blockIdx.x * 256 + threadIdx.x; u < NTOT; u += stride) {
        if (u < NU_ENC) {
            const float* s = enc + u * 8;
            float4 a = *(const float4*)s, bb = *(const float4*)(s + 4);
            ((uint4*)enc_bf)[u] = make_uint4(pk2(a.x, a.y), pk2(a.z, a.w), pk2(bb.x, bb.y), pk2(bb.z, bb.w));
        } else if (u < NU_ENC + NU_WG) {
            long q = u - NU_ENC;
            long rw = q / 384;               // tile-row 0..2047 = wg*64 + r
            int k8 = (int)(q % 384) * 8;
            int wgt = (int)(rw >> 6), r = (int)(rw & 63);
            int gr = ((r >> 4) << 9) + (wgt << 4) + (r & 15);  // type*512 + wg*16 + jj
            const float* s = (k8 < 2560) ? (W_ih + (long)gr * 2560 + k8)
                                         : (W_hh + (long)gr * 512 + (k8 - 2560));
            float4 a = *(const float4*)s, bb = *(const float4*)(s + 4);
            ((uint4*)Wg_bf)[q] = make_uint4(pk2(a.x, a.y), pk2(a.z, a.w), pk2(bb.x, bb.y), pk2(bb.z, bb.w));
        } else if (u < NU_ENC + NU_WG + NU_XE) {
            long q = u - NU_ENC - NU_WG;
            int ku = (int)(q & 63);          // 8-elem chunk within 512
            int b  = (int)((q >> 6) & 63);
            int t  = (int)(q >> 12);         // /4096
            int tok = cap[b * LL + t];
            const float* s = emb + (long)tok * EE + ku * 8;
            float4 a = *(const float4*)s, bb = *(const float4*)(s + 4);
            ((uint4*)xemb)[q] = make_uint4(pk2(a.x, a.y), pk2(a.z, a.w), pk2(bb.x, bb.y), pk2(bb.z, bb.w));
        } else if (u < NU_ENC + NU_WG + NU_XE + NU_GB) {
            long q = u - NU_ENC - NU_WG - NU_XE;
            int i0 = (int)q * 8;
            #pragma unroll
            for (int j = 0; j < 8; ++j) gbias[i0 + j] = b_ih[i0 + j] + b_hh[i0 + j];
        } else if (u < NU_ENC + NU_WG + NU_XE + NU_GB + NU_WHG) {
            long q = u - NU_ENC - NU_WG - NU_XE - NU_GB;
            int rw = (int)(q >> 6);          // 0..2559
            int k8 = (int)(q & 63) * 8;
            const float* s = (rw < 512) ? (W_hid + (long)rw * HH + k8)
                                        : (W_beta + (long)(rw - 512) * HH + k8);
            float4 a = *(const float4*)s, bb = *(const float4*)(s + 4);
            ((uint4*)Whg_bf)[q] = make_uint4(pk2(a.x, a.y), pk2(a.z, a.w), pk2(bb.x, bb.y), pk2(bb.z, bb.w));
        } else {
            long q = u - NU_ENC - NU_WG - NU_XE - NU_GB - NU_WHG;
            int i0 = (int)q * 8;
            #pragma unroll
            for (int j = 0; j < 8; ++j) {
                int i = i0 + j;
                bhg[i] = (i < 512) ? b_hid[i] : b_beta[i - 512];
            }
        }
    }
}

// ---------------- bf16 MFMA GEMM: C = A(MxK) * B(NxK)^T + bias ----------------
template<bool ABF16, bool CBF16>
__global__ __launch_bounds__(256) void gemm_bf16_kernel(
    const void* __restrict__ Av, int lda,
    const float* __restrict__ Bm, int ldb,
    const float* __restrict__ bias,
    float* __restrict__ C, u16* __restrict__ Cbf, int ldc,
    int M, int N, int K,
    const int* __restrict__ caplen, int Tsteps)
{
    __shared__ __align__(16) u16 As[128 * 32];
    __shared__ __align__(16) u16 Bs[128 * 32];
    const int tid  = threadIdx.x;
    const int lane = tid & 63;
    const int w    = tid >> 6;
    const int wr   = w >> 1, wc = w & 1;
    const int bm = blockIdx.y * 128;
    const int bn = blockIdx.x * 128;

    f32x4 acc[4][4];
    #pragma unroll
    for (int m = 0; m < 4; ++m)
        #pragma unroll
        for (int n = 0; n < 4; ++n) acc[m][n] = (f32x4)0.f;

    const int srow = tid >> 1;
    const int scol = (tid & 1) * 16;
    long arow = bm + srow; if (arow >= M) arow = M - 1;
    long brow = bn + srow; if (brow >= N) brow = N - 1;
    const float* apf = ABF16 ? nullptr : (const float*)Av + arow * (long)lda + scol;
    const u16*   apb = ABF16 ? (const u16*)Av + arow * (long)lda + scol : nullptr;
    const float* bp  = Bm + brow * (long)ldb + scol;

    float4 ra[4], rb[4];
    uint4  rab[2];
    if (ABF16) { rab[0] = *(const uint4*)apb; rab[1] = *(const uint4*)(apb + 8); }
    else {
        #pragma unroll
        for (int i = 0; i < 4; ++i) ra[i] = *(const float4*)(apf + 4 * i);
    }
    #pragma unroll
    for (int i = 0; i < 4; ++i) rb[i] = *(const float4*)(bp + 4 * i);

    const int nk = K / 32;
    const int fr = lane & 15;
    const int kc = (lane >> 4) * 8;

    for (int kt = 0; kt < nk; ++kt) {
        uint4 pa0, pa1;
        if (ABF16) { pa0 = rab[0]; pa1 = rab[1]; }
        else {
            pa0 = make_uint4(pk2(ra[0].x, ra[0].y), pk2(ra[0].z, ra[0].w), pk2(ra[1].x, ra[1].y), pk2(ra[1].z, ra[1].w));
            pa1 = make_uint4(pk2(ra[2].x, ra[2].y), pk2(ra[2].z, ra[2].w), pk2(ra[3].x, ra[3].y), pk2(ra[3].z, ra[3].w));
        }
        uint4 pb0 = make_uint4(pk2(rb[0].x, rb[0].y), pk2(rb[0].z, rb[0].w), pk2(rb[1].x, rb[1].y), pk2(rb[1].z, rb[1].w));
        uint4 pb1 = make_uint4(pk2(rb[2].x, rb[2].y), pk2(rb[2].z, rb[2].w), pk2(rb[3].x, rb[3].y), pk2(rb[3].z, rb[3].w));
        __syncthreads();
        *(uint4*)&As[srow * 32 + scol]     = pa0;
        *(uint4*)&As[srow * 32 + scol + 8] = pa1;
        *(uint4*)&Bs[srow * 32 + scol]     = pb0;
        *(uint4*)&Bs[srow * 32 + scol + 8] = pb1;
        if (kt + 1 < nk) {
            bp += 32;
            if (ABF16) { apb += 32; rab[0] = *(const uint4*)apb; rab[1] = *(const uint4*)(apb + 8); }
            else {
                apf += 32;
                #pragma unroll
                for (int i = 0; i < 4; ++i) ra[i] = *(const float4*)(apf + 4 * i);
            }
            #pragma unroll
            for (int i = 0; i < 4; ++i) rb[i] = *(const float4*)(bp + 4 * i);
        }
        __syncthreads();
        bf16x8 a[4], bfr[4];
        #pragma unroll
        for (int m = 0; m < 4; ++m)
            a[m] = *(const bf16x8*)&As[(wr * 64 + m * 16 + fr) * 32 + kc];
        #pragma unroll
        for (int n = 0; n < 4; ++n)
            bfr[n] = *(const bf16x8*)&Bs[(wc * 64 + n * 16 + fr) * 32 + kc];
        #pragma unroll
        for (int m = 0; m < 4; ++m)
            #pragma unroll
            for (int n = 0; n < 4; ++n)
                acc[m][n] = __builtin_amdgcn_mfma_f32_16x16x32_bf16(a[m], bfr[n], acc[m][n], 0, 0, 0);
    }

    const int cr = lane >> 4;
    const int cc = lane & 15;
    #pragma unroll
    for (int n = 0; n < 4; ++n) {
        int gn = bn + wc * 64 + n * 16 + cc;
        if (gn >= N) continue;
        float bv = bias[gn];
        #pragma unroll
        for (int m = 0; m < 4; ++m) {
            int gm0 = bm + wr * 64 + m * 16 + cr * 4;
            #pragma unroll
            for (int r = 0; r < 4; ++r) {
                int gm = gm0 + r;
                if (gm >= M) continue;
                float rowscale = 1.f;
                if (caplen) {
                    int b = gm / Tsteps, tt = gm - b * Tsteps;
                    if (tt >= caplen[b] - 1) rowscale = 0.f;
                }
                float v = (acc[m][n][r] + bv) * rowscale;
                if (CBF16) Cbf[(long)gm * ldc + gn] = f2b(v);
                else       C[(long)gm * ldc + gn] = v;
            }
        }
    }
}

// ---------------- K1: hid + beta-gate via MFMA ----------------
// C(64 x 2560) = h_bf(64x512) @ Whg(2560x512)^T. n<512 -> hid_bf (+b_hid);
// n>=512 -> gv_bf = sigmoid(.+b_beta). Grid 40 wgs x 256; wave v owns n-frag 16.
__global__ __launch_bounds__(256) void hidgate_kernel(
    const u16* __restrict__ h_bf, const u16* __restrict__ Whg, const float* __restrict__ bhg,
    u16* __restrict__ hid_bf, u16* __restrict__ gv_bf)
{
    __shared__ __align__(16) u16 Ash[64 * 512];   // 64KB, XOR-swizzled rows
    const int tid = threadIdx.x, lane = tid & 63, v = tid >> 6;
    const int n0 = blockIdx.x * 64;

    // stage full h (64x512 bf16) into LDS with per-row XOR swizzle
    for (int i = tid; i < 4096; i += 256) {
        int row = i >> 6;
        uint4 val = ((const uint4*)h_bf)[i];
        int byte = i * 16;
        *(uint4*)((char*)Ash + (byte ^ ((row & 7) << 4))) = val;
    }
    __syncthreads();

    f32x4 acc[4];
    #pragma unroll
    for (int m = 0; m < 4; ++m) acc[m] = (f32x4)0.f;

    const u16* wp = Whg + (long)(n0 + v * 16 + (lane & 15)) * 512 + (lane >> 4) * 8;
    bf16x8 bcur = *(const bf16x8*)wp;
    for (int kt = 0; kt < 16; ++kt) {
        bf16x8 bnxt;
        if (kt < 15) bnxt = *(const bf16x8*)(wp + (kt + 1) * 32);
        #pragma unroll
        for (int m = 0; m < 4; ++m) {
            int row = m * 16 + (lane & 15);
            int byte = row * 1024 + kt * 64 + (lane >> 4) * 16;
            bf16x8 af = *(const bf16x8*)((char*)Ash + (byte ^ ((row & 7) << 4)));
            acc[m] = __builtin_amdgcn_mfma_f32_16x16x32_bf16(af, bcur, acc[m], 0, 0, 0);
        }
        bcur = bnxt;
    }

    const int n = n0 + v * 16 + (lane & 15);
    const float bias = bhg[n];
    if (n0 < 512) {
        #pragma unroll
        for (int m = 0; m < 4; ++m) {
            int b0 = m * 16 + (lane >> 4) * 4;
            #pragma unroll
            for (int r = 0; r < 4; ++r)
                hid_bf[(b0 + r) * AA + n] = f2b(acc[m][r] + bias);
        }
    } else {
        #pragma unroll
        for (int m = 0; m < 4; ++m) {
            int b0 = m * 16 + (lane >> 4) * 4;
            #pragma unroll
            for (int r = 0; r < 4; ++r)
                gv_bf[(b0 + r) * DENC + (n - 512)] = f2b(sigmoidf(acc[m][r] + bias));
        }
    }
}

// ---------------- K23: att scores + softmax + ctx (*gate), one wg per b ----------------
__global__ __launch_bounds__(512) void attctx_kernel(
    const u16* __restrict__ enc_att_bf, const u16* __restrict__ hid_bf,
    const float* __restrict__ wf, const float* __restrict__ bfull,
    const u16* __restrict__ enc_bf, const u16* __restrict__ gv_bf,
    u16* __restrict__ ctx_bf, float* __restrict__ out_att,
    const int* __restrict__ caplen, int t)
{
    __shared__ float attS[P];
    __shared__ float red[8];
    const int tid = threadIdx.x, lane = tid & 63, v = tid >> 6;
    const int b = blockIdx.x;
    const int cl = caplen[b];

    // hid + w_full into regs (per 64-lane pattern)
    float hid8[8], wfr[8];
    {
        uint4 hv = *(const uint4*)(hid_bf + b * AA + lane * 8);
        u32 hw[4] = {hv.x, hv.y, hv.z, hv.w};
        #pragma unroll
        for (int q = 0; q < 4; ++q) {
            hid8[2 * q]     = b2f((u16)hw[q]);
            hid8[2 * q + 1] = b2f((u16)(hw[q] >> 16));
        }
        float4 w0 = *(const float4*)(wf + lane * 8);
        float4 w1 = *(const float4*)(wf + lane * 8 + 4);
        wfr[0] = w0.x; wfr[1] = w0.y; wfr[2] = w0.z; wfr[3] = w0.w;
        wfr[4] = w1.x; wfr[5] = w1.y; wfr[6] = w1.z; wfr[7] = w1.w;
    }
    const float bf0 = bfull[0];

    // att scores: wave v handles p = v, v+8, ...
    for (int p = v; p < P; p += 8) {
        uint4 e = *(const uint4*)(enc_att_bf + ((long)(b * P + p)) * AA + lane * 8);
        u32 wd[4] = {e.x, e.y, e.z, e.w};
        float s = 0.f;
        #pragma unroll
        for (int q = 0; q < 4; ++q) {
            float lo = b2f((u16)wd[q]) + hid8[2 * q];
            float hi = b2f((u16)(wd[q] >> 16)) + hid8[2 * q + 1];
            lo = lo > 0.f ? lo : 0.f;
            hi = hi > 0.f ? hi : 0.f;
            s += lo * wfr[2 * q] + hi * wfr[2 * q + 1];
        }
        s = wave_sum(s);
        if (lane == 0) attS[p] = s + bf0;
    }
    __syncthreads();

    // softmax over 196
    float val = (tid < P) ? attS[tid] : -1e30f;
    float mx = val;
    #pragma unroll
    for (int o = 32; o > 0; o >>= 1) mx = fmaxf(mx, __shfl_xor(mx, o, 64));
    if (lane == 0) red[v] = mx;
    __syncthreads();
    mx = red[0];
    #pragma unroll
    for (int i = 1; i < 8; ++i) mx = fmaxf(mx, red[i]);
    float e = (tid < P) ? __expf(val - mx) : 0.f;
    float sw = wave_sum(e);
    __syncthreads();
    if (lane == 0) red[v] = sw;
    __syncthreads();
    float tot = red[0] + red[1] + red[2] + red[3] + red[4] + red[5] + red[6] + red[7];
    float awv = e / tot;
    if (tid < P) {
        attS[tid] = awv;
        out_att[((long)b * TT + t) * P + tid] = (t < cl - 1) ? awv : 0.f;
    }
    __syncthreads();

    // ctx: thread owns 4 d's; deep-unrolled for MLP
    const int d0 = tid * 4;
    const u16* ebase = enc_bf + (long)b * P * DENC + d0;
    float a0 = 0.f, a1 = 0.f, a2 = 0.f, a3 = 0.f;
    #pragma unroll 14
    for (int p = 0; p < P; ++p) {
        uint2 ee = *(const uint2*)(ebase + (long)p * DENC);
        float aa = attS[p];
        a0 += b2f((u16)ee.x) * aa;
        a1 += b2f((u16)(ee.x >> 16)) * aa;
        a2 += b2f((u16)ee.y) * aa;
        a3 += b2f((u16)(ee.y >> 16)) * aa;
    }
    uint2 g = *(const uint2*)(gv_bf + b * DENC + d0);
    float g0 = b2f((u16)g.x), g1 = b2f((u16)(g.x >> 16));
    float g2 = b2f((u16)g.y), g3 = b2f((u16)(g.y >> 16));
    uint2 o;
    o.x = pk2(a0 * g0, a1 * g1);
    o.y = pk2(a2 * g2, a3 * g3);
    *(uint2*)(ctx_bf + (long)b * DENC + d0) = o;
}

// ---------------- Phase D: gates GEMM (MFMA) + LSTM pointwise, fused ----------------
__global__ __launch_bounds__(256) void phaseD_kernel(
    const u16* __restrict__ xemb_t, const u16* __restrict__ ctx_bf, u16* __restrict__ h_bf,
    const u16* __restrict__ Wg_bf, const float* __restrict__ gbias,
    float* __restrict__ c, u16* __restrict__ Hst_bf,
    const int* __restrict__ caplen, int t)
{
    __shared__ __align__(16) u16 As[64 * 128];   // 16KB, swizzled
    __shared__ __align__(16) u16 Bs[64 * 128];   // 16KB
    __shared__ float Gs[64 * 65];                // 16.6KB
    const int tid = threadIdx.x, lane = tid & 63, v = tid >> 6;
    const int wg = blockIdx.x;

    f32x4 acc[4];
    #pragma unroll
    for (int m = 0; m < 4; ++m) acc[m] = (f32x4)0.f;

    const int srow = tid >> 2;            // 0..63
    const int se = (tid & 3) * 32;        // k-elem offset within BK=128
    const u16* wsrc = Wg_bf + ((long)wg * 64 + srow) * 3072 + se;

    auto asrcAt = [&](int k0) -> const u16* {
        int k = k0 + se;
        if (k < 512)  return xemb_t + srow * EE + k;
        if (k < 2560) return ctx_bf + srow * DENC + (k - 512);
        return h_bf + srow * HH + (k - 2560);
    };

    uint4 ra[4], rw[4];
    {
        const u16* as = asrcAt(0);
        #pragma unroll
        for (int i = 0; i < 4; ++i) { ra[i] = *(const uint4*)(as + 8 * i); rw[i] = *(const uint4*)(wsrc + 8 * i); }
    }

    const int swz = (srow & 7) << 4;
    for (int kt = 0; kt < 24; ++kt) {
        __syncthreads();
        #pragma unroll
        for (int i = 0; i < 4; ++i) {
            int cb = se * 2 + i * 16;
            *(uint4*)((char*)As + srow * 256 + (cb ^ swz)) = ra[i];
            *(uint4*)((char*)Bs + srow * 256 + (cb ^ swz)) = rw[i];
        }
        if (kt + 1 < 24) {
            int k0n = (kt + 1) * 128;
            const u16* as = asrcAt(k0n);
            const u16* ws = wsrc + k0n;
            #pragma unroll
            for (int i = 0; i < 4; ++i) { ra[i] = *(const uint4*)(as + 8 * i); rw[i] = *(const uint4*)(ws + 8 * i); }
        }
        __syncthreads();
        #pragma unroll
        for (int kf = 0; kf < 4; ++kf) {
            int fb = kf * 64 + (lane >> 4) * 16;
            int rb_ = v * 16 + (lane & 15);
            bf16x8 bfrag = *(const bf16x8*)((char*)Bs + rb_ * 256 + (fb ^ ((rb_ & 7) << 4)));
            #pragma unroll
            for (int m = 0; m < 4; ++m) {
                int rowa = m * 16 + (lane & 15);
                bf16x8 afrag = *(const bf16x8*)((char*)As + rowa * 256 + (fb ^ ((rowa & 7) << 4)));
                acc[m] = __builtin_amdgcn_mfma_f32_16x16x32_bf16(afrag, bfrag, acc[m], 0, 0, 0);
            }
        }
    }

    {
        int r = v * 16 + (lane & 15);
        #pragma unroll
        for (int m = 0; m < 4; ++m) {
            int brow = m * 16 + (lane >> 4) * 4;
            #pragma unroll
            for (int rg = 0; rg < 4; ++rg)
                Gs[r * 65 + brow + rg] = acc[m][rg];
        }
    }
    __syncthreads();

    const int b = lane;
    #pragma unroll
    for (int i = 0; i < 4; ++i) {
        int jj = v * 4 + i;
        int j = wg * 16 + jj;
        float gi = Gs[jj * 65 + b]        + gbias[j];
        float gf = Gs[(16 + jj) * 65 + b] + gbias[512 + j];
        float gg = Gs[(32 + jj) * 65 + b] + gbias[1024 + j];
        float go = Gs[(48 + jj) * 65 + b] + gbias[1536 + j];
        float cold = c[b * HH + j];
        float cn = sigmoidf(gf) * cold + sigmoidf(gi) * tanhf(gg);
        float hn = sigmoidf(go) * tanhf(cn);
        Hst_bf[((long)b * TT + t) * HH + j] = f2b(hn);
        if (t < caplen[b] - 1) {
            c[b * HH + j] = cn;
            h_bf[b * HH + j] = f2b(hn);
        }
    }
}

// ---------------- meta outputs ----------------
__global__ __launch_bounds__(256) void meta_kernel(const int* __restrict__ cap, const int* __restrict__ caplen,
                                                   float* __restrict__ out_cap, float* __restrict__ out_len) {
    int i = blockIdx.x * 256 + threadIdx.x;
    if (i < B * LL) out_cap[i] = (float)cap[i];
    if (i < B) out_len[i] = (float)(caplen[i] - 1);
}

extern "C" void kernel_launch(void* const* d_in, const int* in_sizes, int n_in,
                              void* d_out, int out_size, void* d_ws, size_t ws_size,
                              hipStream_t stream) {
    const float* enc    = (const float*)d_in[0];
    const int*   cap    = (const int*)d_in[1];
    const int*   caplen = (const int*)d_in[2];
    const float* emb    = (const float*)d_in[3];
    const float* W_enc  = (const float*)d_in[4];
    const float* b_enc  = (const float*)d_in[5];
    const float* W_hid  = (const float*)d_in[6];
    const float* b_hid  = (const float*)d_in[7];
    const float* w_full = (const float*)d_in[8];
    const float* b_full = (const float*)d_in[9];
    const float* W_ih   = (const float*)d_in[10];
    const float* b_ih   = (const float*)d_in[11];
    const float* W_hh   = (const float*)d_in[12];
    const float* b_hh   = (const float*)d_in[13];
    const float* W_h0   = (const float*)d_in[14];
    const float* b_h0   = (const float*)d_in[15];
    const float* W_c0   = (const float*)d_in[16];
    const float* b_c0   = (const float*)d_in[17];
    const float* W_beta = (const float*)d_in[18];
    const float* b_beta = (const float*)d_in[19];
    const float* W_fc   = (const float*)d_in[20];
    const float* b_fc   = (const float*)d_in[21];

    float* out = (float*)d_out;
    float* out_pred = out;                                  // 14,720,000
    float* out_cap  = out + 14720000;                       // 1536
    float* out_len  = out + 14721536;                       // 64
    float* out_att  = out + 14721600;                       // 288,512

    // Scratch inside out_pred (dead until the final vocab GEMM overwrites it):
    u16*   enc_bf = (u16*)out_pred;                         // 12,845,056 fl
    u16*   xemb   = (u16*)(out + 12845056);                 // 376,832 fl
    float* mean   = out + 13221888;                         // 131,072 fl (< 14,720,000)

    float* ws = (float*)d_ws;
    u16*   Wg_bf      = (u16*)ws;                           // 3,145,728 fl
    float* gbias      = ws + 3145728;                       // 2,048
    float* c          = ws + 3147776;                       // 32,768
    u16*   h_bf       = (u16*)(ws + 3180544);               // 16,384 fl
    u16*   ctx_bf     = (u16*)(ws + 3196928);               // 65,536 fl
    u16*   Hst_bf     = (u16*)(ws + 3262464);               // 376,832 fl
    u16*   enc_att_bf = (u16*)(ws + 3639296);               // 3,211,264 fl
    u16*   Whg_bf     = (u16*)(ws + 6850560);               // 655,360 fl
    float* bhg        = ws + 7505920;                       // 2,560
    u16*   hid_bf     = (u16*)(ws + 7508480);               // 16,384 fl
    u16*   gv_bf      = (u16*)(ws + 7524864);               // 65,536 fl -> total 7,590,400 fl (30.4MB)

    // ---- prologue ----
    mean_kernel<<<dim3(DENC / 256, B), 256, 0, stream>>>(enc, mean);
    h0c0_kernel<<<16384, 256, 0, stream>>>(mean, W_h0, b_h0, W_c0, b_c0, c, h_bf);
    prep_kernel<<<4096, 256, 0, stream>>>(enc, W_ih, W_hh, b_ih, b_hh, emb, cap,
                                          W_hid, W_beta, b_hid, b_beta,
                                          enc_bf, Wg_bf, xemb, gbias, Whg_bf, bhg);
    gemm_bf16_kernel<false, true><<<dim3(AA / 128, (B * P) / 128), 256, 0, stream>>>(
        enc, DENC, W_enc, DENC, b_enc, nullptr, enc_att_bf, AA, B * P, AA, DENC, nullptr, 0);
    meta_kernel<<<(B * LL + 255) / 256, 256, 0, stream>>>(cap, caplen, out_cap, out_len);

    // ---- recurrent steps: 3 launches per step ----
    for (int t = 0; t < TT; ++t) {
        hidgate_kernel<<<40, 256, 0, stream>>>(h_bf, Whg_bf, bhg, hid_bf, gv_bf);
        attctx_kernel<<<B, 512, 0, stream>>>(enc_att_bf, hid_bf, w_full, b_full,
                                             enc_bf, gv_bf, ctx_bf, out_att, caplen, t);
        phaseD_kernel<<<32, 256, 0, stream>>>(xemb + (long)t * B * EE, ctx_bf, h_bf,
                                              Wg_bf, gbias, c, Hst_bf, caplen, t);
    }

    // ---- deferred vocab FC: preds = Hst(1472x512,bf16) @ W_fc(10000x512)^T + b_fc ----
    gemm_bf16_kernel<true, false><<<dim3((VV + 127) / 128, (B * TT + 127) / 128), 256, 0, stream>>>(
        Hst_bf, HH, W_fc, HH, b_fc, out_pred, nullptr, VV, B * TT, VV, HH, caplen, TT);
}